// Round 9
// baseline (390.510 us; speedup 1.0000x reference)
//
#include <hip/hip_runtime.h>

// DiffeomorphicTransform: flow = velocity/2^7; 7x { grid = sample_grid + flow*rf;
// flow = flow + trilerp(flow, grid) }  (border clamp, align_corners=True)
//
// R9 = R8 with 4 x-adjacent voxels per channel-thread. Ablation so far:
// traffic is solved (FETCH 21.7 MB, z-slab XCD swizzle); late dispatches sit
// near the L1 line-throughput roofline (~64 lines/gather at +-40-voxel white
// scatter), early ones are issue/latency-bound. 4-vox cuts vmem instr per
// voxel-channel 6->5 and quadruples base/store vectorization, while
// channel-split keeps live state (~16 fpair results) under the spill line
// that serialized R2/R7. Analytic identity grid + deferred scale retained.

constexpr int D = 128, H = 160, W = 128;
constexpr int N = D * H * W;               // 2,621,440 voxels
constexpr int QUADS = N / 4;               // 655,360 x-quads
constexpr int QUAD_BLOCKS = QUADS / 256;   // 2560 quad-chunks (1024 voxels each)
constexpr int NUM_XCD = 8;
constexpr int CHUNKS_PER_XCD = QUAD_BLOCKS / NUM_XCD;   // 320

// 4-byte-aligned float pair (x-adjacent corners)
struct __attribute__((packed)) fpair { float lo, hi; };

__global__ __launch_bounds__(256)
void diffeo_step(const float* __restrict__ src,   // [3][N] flow (deferred scale)
                 const float* __restrict__ rf_p,  // scalar range_flow
                 float* __restrict__ dst,         // [3][N]
                 float scale)                     // 1/128 on step 1, else 1.0
{
    // z-slab XCD swizzle (R6-validated): XCD = blockIdx%8 owns a contiguous
    // slab walked sequentially, 3 channels of each chunk back-to-back.
    const int b   = blockIdx.x;              // 0..7679
    const int xcd = b & (NUM_XCD - 1);
    const int k   = b >> 3;                  // 0..959
    const int bc  = k % 3;                   // channel (block-uniform)
    const int s_  = k / 3;                   // slab-local chunk 0..319
    const int qb  = xcd * CHUNKS_PER_XCD + s_;   // quad-chunk 0..2559
    const int t   = qb * 256 + threadIdx.x;      // quad id [0, QUADS)
    const int i0  = 4 * t;                       // first voxel (x%4==0, same row)

    const float rf = rf_p[0];

    // voxel coords (W=128 pow2; quad never crosses a row: x<=124)
    const int x = i0 & (W - 1);
    const int r = i0 >> 7;                   // z*H + y
    const int y = r % H;
    const int z = r / H;

    // coalesced float4 base loads, all 3 components for all 4 voxels
    const float4 f0 = ((const float4*)(src))[t];
    const float4 f1 = ((const float4*)(src + N))[t];
    const float4 f2 = ((const float4*)(src + 2 * N))[t];

    const float sxw = rf * 0.5f * (float)(W - 1);
    const float syw = rf * 0.5f * (float)(H - 1);
    const float szw = rf * 0.5f * (float)(D - 1);

    const float fxv[4] = {f0.x, f0.y, f0.z, f0.w};
    const float fyv[4] = {f1.x, f1.y, f1.z, f1.w};
    const float fzv[4] = {f2.x, f2.y, f2.z, f2.w};

    float wxa[4], wya[4], wza[4], fca[4];
    int   ofs[4][4];
    bool  hix[4];

#pragma unroll
    for (int j = 0; j < 4; ++j) {
        const float fx = fxv[j] * scale;
        const float fy = fyv[j] * scale;
        const float fz = fzv[j] * scale;
        fca[j] = (bc == 0) ? fx : (bc == 1) ? fy : fz;

        const float ix = fminf(fmaxf((float)(x + j) + fx * sxw, 0.0f), (float)(W - 1));
        const float iy = fminf(fmaxf((float)y       + fy * syw, 0.0f), (float)(H - 1));
        const float iz = fminf(fmaxf((float)z       + fz * szw, 0.0f), (float)(D - 1));

        const float x0f = floorf(ix), y0f = floorf(iy), z0f = floorf(iz);
        wxa[j] = ix - x0f; wya[j] = iy - y0f; wza[j] = iz - z0f;
        const int x0 = (int)x0f, y0 = (int)y0f, z0 = (int)z0f;
        const int y1 = min(y0 + 1, H - 1);
        const int z1 = min(z0 + 1, D - 1);

        // pair-load base: x0==W-1 implies wx==0 (x1==x0), select .hi — exact.
        const int xb = min(x0, W - 2);
        hix[j] = (x0 == W - 1);

        ofs[j][0] = (z0 * H + y0) * W + xb;
        ofs[j][1] = (z0 * H + y1) * W + xb;
        ofs[j][2] = (z1 * H + y0) * W + xb;
        ofs[j][3] = (z1 * H + y1) * W + xb;
    }

    // 16 independent 8B gathers
    const float* __restrict__ s = src + bc * N;
    fpair p[4][4];
#pragma unroll
    for (int j = 0; j < 4; ++j)
#pragma unroll
        for (int q = 0; q < 4; ++q)
            p[j][q] = *(const fpair*)(s + ofs[j][q]);

    float outv[4];
#pragma unroll
    for (int j = 0; j < 4; ++j) {
        const float wx = wxa[j], wy = wya[j], wz = wza[j];
        const float omx = 1.0f - wx, omy = 1.0f - wy, omz = 1.0f - wz;
        const float v00 = hix[j] ? p[j][0].hi : p[j][0].lo;
        const float v01 = hix[j] ? p[j][1].hi : p[j][1].lo;
        const float v10 = hix[j] ? p[j][2].hi : p[j][2].lo;
        const float v11 = hix[j] ? p[j][3].hi : p[j][3].lo;
        const float v = omz * (omy * (omx * v00 + wx * p[j][0].hi)
                             + wy  * (omx * v01 + wx * p[j][1].hi))
                      + wz  * (omy * (omx * v10 + wx * p[j][2].hi)
                             + wy  * (omx * v11 + wx * p[j][3].hi));
        outv[j] = fca[j] + v * scale;    // deferred scale (trilerp linear)
    }

    ((float4*)(dst + bc * N))[t] = make_float4(outv[0], outv[1], outv[2], outv[3]);
}

extern "C" void kernel_launch(void* const* d_in, const int* in_sizes, int n_in,
                              void* d_out, int out_size, void* d_ws, size_t ws_size,
                              hipStream_t stream)
{
    const float* vel = (const float*)d_in[0];   // [1,3,128,160,128]
    const float* rf  = (const float*)d_in[2];   // scalar range_flow
    float* out = (float*)d_out;                 // [1,3,128,160,128]
    float* ws  = (float*)d_ws;                  // needs 3*N*4 = 31.5 MB

    const dim3 blk(256);
    const dim3 grd(3 * QUAD_BLOCKS);            // 7680 blocks

    // step 1: velocity (deferred /128) -> out
    diffeo_step<<<grd, blk, 0, stream>>>(vel, rf, out, 1.0f / 128.0f);
    // steps 2..7 ping-pong: out->ws, ws->out, ... ; step 7 ends in d_out
    float* bufs[2] = {out, ws};
    for (int it = 2; it <= 7; ++it) {
        float* s = bufs[it & 1];
        float* d = bufs[(it + 1) & 1];
        diffeo_step<<<grd, blk, 0, stream>>>(s, rf, d, 1.0f);
    }
}

// Round 10
// 297.890 us; speedup vs baseline: 1.3109x; 1.3109x over previous
//
#include <hip/hip_runtime.h>

// DiffeomorphicTransform: flow = velocity/2^7; 7x { grid = sample_grid + flow*rf;
// flow = flow + trilerp(flow, grid) }  (border clamp, align_corners=True)
//
// R10: channel-INTERLEAVED intermediate layout [N][3]. R8's late dispatches are
// bound by gather line fan-out on the L2/L3 fabric (~2.0 GB/dispatch: white
// +-25-voxel scatter => 1 line per corner per channel, planar pays 3 lines per
// corner). Interleaving puts all 3 channels of a corner-pair in 24 contiguous
// bytes => ~5.2 lines/voxel vs 12, and merges to 1 thread/voxel at only 12
// vmem instrs/voxel (vs 18 across R8's channel-split trio). Repack prologue
// (planar->interleaved, exact /128 folded) + planar-store final step.
// Keeps z-slab XCD swizzle (R6) + analytic identity grid (R3).

constexpr int D = 128, H = 160, W = 128;
constexpr int N = D * H * W;             // 2,621,440 voxels
constexpr int VOX_BLOCKS = N / 256;      // 10240 blocks
constexpr int NUM_XCD = 8;
constexpr int CHUNKS_PER_XCD = VOX_BLOCKS / NUM_XCD;   // 1280

__global__ __launch_bounds__(256)
void repack_scale(const float* __restrict__ vel,   // [3][N] planar
                  float3* __restrict__ dst3)       // [N][3] interleaved
{
    const int i = blockIdx.x * blockDim.x + threadIdx.x;
    const float s = 1.0f / 128.0f;                 // 2^-7, exact
    dst3[i] = make_float3(vel[i] * s, vel[i + N] * s, vel[i + 2 * N] * s);
}

template <bool PLANAR_OUT>
__global__ __launch_bounds__(256)
void diffeo_step(const float3* __restrict__ src3,  // [N][3] flow
                 const float* __restrict__ rf_p,   // scalar range_flow
                 void* __restrict__ dst_raw)       // [N][3] or planar [3][N]
{
    // z-slab XCD swizzle (R6-validated)
    const int b   = blockIdx.x;              // 0..10239
    const int xcd = b & (NUM_XCD - 1);
    const int k   = b >> 3;                  // 0..1279
    const int vb  = xcd * CHUNKS_PER_XCD + k;
    const int i   = vb * 256 + threadIdx.x;  // voxel id [0,N)

    const float rf = rf_p[0];

    // voxel coords (W=128 pow2)
    const int x = i & (W - 1);
    const int r = i >> 7;                    // z*H + y
    const int y = r % H;
    const int z = r / H;

    const float3 f = src3[i];                // this voxel's flow (all channels)

    // analytic identity grid: unnormalized coord = x + flow*rf*0.5*(dim-1)
    const float ix = fminf(fmaxf((float)x + f.x * (rf * 0.5f * (float)(W - 1)), 0.0f), (float)(W - 1));
    const float iy = fminf(fmaxf((float)y + f.y * (rf * 0.5f * (float)(H - 1)), 0.0f), (float)(H - 1));
    const float iz = fminf(fmaxf((float)z + f.z * (rf * 0.5f * (float)(D - 1)), 0.0f), (float)(D - 1));

    const float x0f = floorf(ix), y0f = floorf(iy), z0f = floorf(iz);
    const float wx = ix - x0f, wy = iy - y0f, wz = iz - z0f;
    const int x0 = (int)x0f, y0 = (int)y0f, z0 = (int)z0f;
    const int y1 = min(y0 + 1, H - 1);
    const int z1 = min(z0 + 1, D - 1);

    // corner-pair base: x0==W-1 implies wx==0 (x1==x0) -> select hi triplet.
    const int xb = min(x0, W - 2);
    const bool hix = (x0 == W - 1);

    int ofs[4];
    ofs[0] = (z0 * H + y0) * W + xb;
    ofs[1] = (z0 * H + y1) * W + xb;
    ofs[2] = (z1 * H + y0) * W + xb;
    ofs[3] = (z1 * H + y1) * W + xb;

    // 8 gathers: per row-corner, two adjacent float3 triplets (24 contiguous
    // bytes covering x0 and x1 for ALL 3 channels -> ~1 line per row-corner)
    float3 p0[4], p1[4];
#pragma unroll
    for (int q = 0; q < 4; ++q) {
        p0[q] = src3[ofs[q]];
        p1[q] = src3[ofs[q] + 1];
    }
    if (hix) {
#pragma unroll
        for (int q = 0; q < 4; ++q) p0[q] = p1[q];   // wx==0 here, exact
    }

    const float omx = 1.0f - wx, omy = 1.0f - wy, omz = 1.0f - wz;
    const float w00 = omz * omy, w01 = omz * wy, w10 = wz * omy, w11 = wz * wy;

    // bilinear over (z,y) of the x-lerped corner values, per channel
    const float vx = w00 * (omx * p0[0].x + wx * p1[0].x)
                   + w01 * (omx * p0[1].x + wx * p1[1].x)
                   + w10 * (omx * p0[2].x + wx * p1[2].x)
                   + w11 * (omx * p0[3].x + wx * p1[3].x);
    const float vy = w00 * (omx * p0[0].y + wx * p1[0].y)
                   + w01 * (omx * p0[1].y + wx * p1[1].y)
                   + w10 * (omx * p0[2].y + wx * p1[2].y)
                   + w11 * (omx * p0[3].y + wx * p1[3].y);
    const float vz = w00 * (omx * p0[0].z + wx * p1[0].z)
                   + w01 * (omx * p0[1].z + wx * p1[1].z)
                   + w10 * (omx * p0[2].z + wx * p1[2].z)
                   + w11 * (omx * p0[3].z + wx * p1[3].z);

    const float o0 = f.x + vx, o1 = f.y + vy, o2 = f.z + vz;

    if (PLANAR_OUT) {
        float* __restrict__ dp = (float*)dst_raw;
        dp[i] = o0; dp[i + N] = o1; dp[i + 2 * N] = o2;
    } else {
        ((float3*)dst_raw)[i] = make_float3(o0, o1, o2);
    }
}

extern "C" void kernel_launch(void* const* d_in, const int* in_sizes, int n_in,
                              void* d_out, int out_size, void* d_ws, size_t ws_size,
                              hipStream_t stream)
{
    const float* vel = (const float*)d_in[0];   // [1,3,128,160,128] planar
    const float* rf  = (const float*)d_in[2];   // scalar range_flow
    float3* out3 = (float3*)d_out;              // d_out reused as interleaved scratch
    float3* ws3  = (float3*)d_ws;               // 31.5 MB interleaved buffer

    const dim3 blk(256);
    const dim3 grd(VOX_BLOCKS);                 // 10240 blocks

    // prologue: planar velocity -> interleaved ws, exact /2^7 folded in
    repack_scale<<<grd, blk, 0, stream>>>(vel, ws3);

    // steps 1..6 ping-pong interleaved: ws->out3->ws->out3->ws->out3->ws
    diffeo_step<false><<<grd, blk, 0, stream>>>(ws3,  rf, out3);   // s1
    diffeo_step<false><<<grd, blk, 0, stream>>>(out3, rf, ws3);    // s2
    diffeo_step<false><<<grd, blk, 0, stream>>>(ws3,  rf, out3);   // s3
    diffeo_step<false><<<grd, blk, 0, stream>>>(out3, rf, ws3);    // s4
    diffeo_step<false><<<grd, blk, 0, stream>>>(ws3,  rf, out3);   // s5
    diffeo_step<false><<<grd, blk, 0, stream>>>(out3, rf, ws3);    // s6
    // step 7: interleaved ws -> PLANAR d_out (full overwrite, no aliasing)
    diffeo_step<true ><<<grd, blk, 0, stream>>>(ws3,  rf, d_out);  // s7
}